// Round 3
// baseline (342.362 us; speedup 1.0000x reference)
//
#include <hip/hip_runtime.h>

// iSTFT as fold + bf16 MFMA GEMM.
//
// full[f,t] Hermitian -> f=0..512 with weight wt = {1,2,...,2,1}/1024.
// Output l = 256*s + j (s=2..2002, j=0..255) covered by frames t=s-3..s (clipped).
// e^{i*2pi*f*(j+256k)/1024} = e^{i*2pi*f*j/1024} * i^{f*k}
//   V_s[f] = sum_k full[f,s-k] * i^{f*k}            (fold, done in GEMM kernel)
//   y_full[s*256+j] = sum_f [wt*ReV*cos(th) - wt*ImV*sin(th)],  th = 2pi f j/1024
// => GEMM: A[seg][k] (k=2f: ReV, k=2f+1: ImV)  x  W[k][j] (2f: wt*cos, 2f+1: -wt*sin)
// K padded 1026 -> 1088 (17 chunks of 64). Output / frame-count, one write per elem.

typedef short bf16x8 __attribute__((ext_vector_type(8)));
typedef float f32x4  __attribute__((ext_vector_type(4)));

constexpr int NFFT = 1024, HOP = 256, NFREQ = 513, TFR = 2000;
constexpr int NB = 16, NSEG = 2001, OUTLEN = NSEG * HOP;
constexpr int NCHUNK = 17;                    // K chunks of 64 (= 32 freq pairs)
constexpr int CHUNK_BYTES = 256 * 128;        // Bt chunk image: 256 j-rows x 128 B
constexpr size_t WS_NEED = (size_t)NCHUNK * CHUNK_BYTES;   // 557056 B

__device__ inline short f2bf(float x) {      // RNE float->bf16 (finite inputs)
    unsigned u = __float_as_uint(x);
    unsigned r = (u + 0x7fffu + ((u >> 16) & 1u)) >> 16;
    return (short)r;
}

// ---- kernel 1: basis, stored as the swizzled LDS image per chunk ----
// Wt[j][k] bf16, row j = 128 B; byte within row for freq-pair fl: (fl*4)^((j&7)<<4)
__global__ void build_basis(char* __restrict__ bw) {
    int id = blockIdx.x * 256 + threadIdx.x;  // 17 * 8192 total
    int c = id >> 13, r = id & 8191, j = r >> 5, fl = r & 31;
    int f = c * 32 + fl;
    float re = 0.f, im = 0.f;
    if (f < NFREQ) {
        float wt = (f == 0 || f == NFFT / 2) ? (1.0f / NFFT) : (2.0f / NFFT);
        int p = (f * j) & (NFFT - 1);                 // exact phase reduction
        float ang = (float)p * 6.135923151542565e-03f; // 2*pi/1024
        float s, cs;
        sincosf(ang, &s, &cs);
        re = wt * cs;
        im = -wt * s;
    }
    int off = c * CHUNK_BYTES + j * 128 + ((fl * 4) ^ ((j & 7) << 4));
    *(short2*)(bw + off) = make_short2(f2bf(re), f2bf(im));
}

// ---- kernel 2: fold + GEMM ----
// block: 256 thr = 4 waves (2x2).  tile: 64 segs x 256 j.  K-chunk 64.
__global__ __launch_bounds__(256) void istft_mfma(const float* __restrict__ stft,
                                                  const char* __restrict__ bw,
                                                  float* __restrict__ out) {
    __shared__ float4 smem4[(CHUNK_BYTES + 64 * 128) / 16];  // 32KB Bt + 8KB A
    char* sB = (char*)smem4;
    char* sA = sB + CHUNK_BYTES;

    const int tid  = threadIdx.x;
    const int tile = blockIdx.x, b = blockIdx.y;
    const int wid  = tid >> 6, lane = tid & 63;
    const int wr   = wid >> 1, wc = wid & 1;

    const float* fb = stft + (size_t)b * NFREQ * (TFR * 2);

    f32x4 acc[2][8] = {};

    for (int c = 0; c < NCHUNK; ++c) {
        __syncthreads();  // prev chunk's readers done before overwrite

        // stage Bt chunk (global image == LDS image, linear copy)
        const float4* src = (const float4*)(bw + (size_t)c * CHUNK_BYTES);
#pragma unroll
        for (int i = 0; i < 8; ++i) smem4[i * 256 + tid] = src[i * 256 + tid];

        // fold A tile: 64 segs x 32 freq-pairs, 8 elements/thread
#pragma unroll
        for (int e = 0; e < 8; ++e) {
            int lin = e * 256 + tid;
            int sl = lin >> 5, fl = lin & 31;
            int f = c * 32 + fl;
            float vr = 0.f, vi = 0.f;
            if (f < NFREQ) {
                const float* frow = fb + (size_t)f * (TFR * 2);
                int s = tile * 64 + sl + 2;
#pragma unroll
                for (int k = 0; k < 4; ++k) {
                    int t = s - k;
                    if (t >= 0 && t < TFR) {
                        float2 v = *(const float2*)(frow + 2 * t);
                        int e2 = (f * k) & 3;  // * i^e2
                        float ar = (e2 == 0) ? v.x : (e2 == 1) ? -v.y : (e2 == 2) ? -v.x :  v.y;
                        float ai = (e2 == 0) ? v.y : (e2 == 1) ?  v.x : (e2 == 2) ? -v.y : -v.x;
                        vr += ar; vi += ai;
                    }
                }
            }
            int off = sl * 128 + ((fl * 4) ^ ((sl & 7) << 4));
            *(short2*)(sA + off) = make_short2(f2bf(vr), f2bf(vi));
        }
        __syncthreads();

        // MFMA: per wave 2 m-frags x 8 n-frags x 2 k-frags
#pragma unroll
        for (int kf = 0; kf < 2; ++kf) {
            int kbx = (kf * 64 + (lane >> 4) * 16) ^ ((lane & 7) << 4);
            int arow = (wr * 32 + (lane & 15)) * 128;
            bf16x8 a0 = *(const bf16x8*)(sA + arow + kbx);
            bf16x8 a1 = *(const bf16x8*)(sA + arow + 16 * 128 + kbx);
#pragma unroll
            for (int ni = 0; ni < 8; ++ni) {
                int jrow = (wc * 128 + ni * 16 + (lane & 15)) * 128;
                bf16x8 bf = *(const bf16x8*)(sB + jrow + kbx);
                acc[0][ni] = __builtin_amdgcn_mfma_f32_16x16x32_bf16(a0, bf, acc[0][ni], 0, 0, 0);
                acc[1][ni] = __builtin_amdgcn_mfma_f32_16x16x32_bf16(a1, bf, acc[1][ni], 0, 0, 0);
            }
        }
    }

    // epilogue: C/D layout col=lane&15, row=(lane>>4)*4+reg
#pragma unroll
    for (int mi = 0; mi < 2; ++mi) {
#pragma unroll
        for (int r = 0; r < 4; ++r) {
            int sl = wr * 32 + mi * 16 + (lane >> 4) * 4 + r;
            int seg = tile * 64 + sl;
            if (seg >= NSEG) continue;
            int s = seg + 2;
            int lo = s - 3; lo = lo < 0 ? 0 : lo;
            int hi = s > (TFR - 1) ? (TFR - 1) : s;
            float inv = 1.0f / (float)(hi - lo + 1);
            size_t base = (size_t)b * OUTLEN + (size_t)seg * 256 + wc * 128 + (lane & 15);
#pragma unroll
            for (int ni = 0; ni < 8; ++ni)
                out[base + ni * 16] = acc[mi][ni][r] * inv;
        }
    }
}

// ---- fallback (ws too small): direct VALU kernel from round 0 ----
__global__ __launch_bounds__(256, 4) void istft_seg_kernel(
    const float* __restrict__ stft, float* __restrict__ out)
{
    __shared__ float2 V[NFREQ];
    const int blk = blockIdx.x;
    const int b = blk / NSEG;
    const int s = (blk % NSEG) + 2;
    const int tid = threadIdx.x;

    const float* fbase = stft + (size_t)b * (size_t)NFREQ * (TFR * 2);
    for (int f = tid; f < NFREQ; f += 256) {
        const float* frow = fbase + (size_t)f * (TFR * 2);
        float vr = 0.0f, vi = 0.0f;
#pragma unroll
        for (int k = 0; k < 4; ++k) {
            int t = s - k;
            if (t < 0 || t >= TFR) continue;
            float2 v = *(const float2*)(frow + 2 * t);
            int e = (f * k) & 3;
            float ar = (e == 0) ? v.x : (e == 1) ? -v.y : (e == 2) ? -v.x :  v.y;
            float ai = (e == 0) ? v.y : (e == 1) ?  v.x : (e == 2) ? -v.y : -v.x;
            vr += ar; vi += ai;
        }
        float scale = (f == 0 || f == NFFT / 2) ? (1.0f / NFFT) : (2.0f / NFFT);
        V[f] = make_float2(vr * scale, vi * scale);
    }
    __syncthreads();

    int tlo = s - 3; if (tlo < 0) tlo = 0;
    int thi = s;     if (thi > TFR - 1) thi = TFR - 1;
    const float inv_w = 1.0f / (float)(thi - tlo + 1);

    const int j = tid;
    double ang = (2.0 * 3.14159265358979323846 / (double)NFFT) * (double)j;
    const float cd = (float)cos(ang);
    const float sd = (float)sin(ang);

    float cc = 1.0f, sn = 0.0f, a = 0.0f;
#pragma unroll 4
    for (int f = 0; f < NFREQ; ++f) {
        float2 v = V[f];
        a = fmaf(v.x, cc, a);
        a = fmaf(-v.y, sn, a);
        float cn = fmaf(cc, cd, -(sn * sd));
        sn       = fmaf(sn, cd,  (cc * sd));
        cc = cn;
    }
    out[(size_t)b * OUTLEN + (size_t)(s - 2) * HOP + j] = a * inv_w;
}

extern "C" void kernel_launch(void* const* d_in, const int* in_sizes, int n_in,
                              void* d_out, int out_size, void* d_ws, size_t ws_size,
                              hipStream_t stream)
{
    const float* stft = (const float*)d_in[0];
    float* out = (float*)d_out;

    if (ws_size >= WS_NEED) {
        char* bw = (char*)d_ws;
        build_basis<<<dim3(NCHUNK * 8192 / 256), dim3(256), 0, stream>>>(bw);
        istft_mfma<<<dim3(32, NB), dim3(256), 0, stream>>>(stft, bw, out);
    } else {
        istft_seg_kernel<<<dim3(NB * NSEG), dim3(256), 0, stream>>>(stft, out);
    }
}

// Round 5
// 252.001 us; speedup vs baseline: 1.3586x; 1.3586x over previous
//
#include <hip/hip_runtime.h>

// iSTFT as fold + bf16 MFMA GEMM (round 4: coalesced fold, 8-wave blocks).
//
// full[f,t] Hermitian -> f=0..512, weight wt={1,2,..,2,1}/1024 folded into basis.
// Output l = 256*s + j (s=2..2002, j=0..255) covered by frames t=s-3..s (clipped).
//   V_s[f] = sum_k full[f,s-k] * i^{f*k}
//   y[seg*256+j] = sum_f [wt*ReV*cos - wt*ImV*sin] / wss
// GEMM: A[seg][k] (k=2f:Re, 2f+1:Im) x W[k][j];  K 1026 -> 1088 (17 chunks of 64).
// Fold lane-mapping: lanes = 64 consecutive segments for a wave-uniform f
// => every fold load is 512 B contiguous. f&3 == unroll index i => static signs.

typedef short bf16x8 __attribute__((ext_vector_type(8)));
typedef float f32x4  __attribute__((ext_vector_type(4)));

constexpr int NFFT = 1024, HOP = 256, NFREQ = 513, TFR = 2000;
constexpr int NB = 16, NSEG = 2001, OUTLEN = NSEG * HOP;
constexpr int NCHUNK = 17;                    // K chunks of 64 (= 32 freq pairs)
constexpr int CHUNK_BYTES = 256 * 128;        // Bt chunk image: 256 j-rows x 128 B
constexpr int NTILE = 32;                     // 32 tiles x 64 segs covers 2001
constexpr size_t WS_NEED = (size_t)NCHUNK * CHUNK_BYTES;   // 557056 B

__device__ inline short f2bf(float x) {      // RNE float->bf16 (finite inputs)
    unsigned u = __float_as_uint(x);
    unsigned r = (u + 0x7fffu + ((u >> 16) & 1u)) >> 16;
    return (short)r;
}

// ---- kernel 1: basis, stored as the swizzled LDS image per chunk ----
// Wt[j][k] bf16, row j = 128 B; byte within row for freq-pair fl: (fl*4)^((j&7)<<4)
__global__ void build_basis(char* __restrict__ bw) {
    int id = blockIdx.x * 256 + threadIdx.x;  // 17 * 8192 total
    int c = id >> 13, r = id & 8191, j = r >> 5, fl = r & 31;
    int f = c * 32 + fl;
    float re = 0.f, im = 0.f;
    if (f < NFREQ) {
        float wt = (f == 0 || f == NFFT / 2) ? (1.0f / NFFT) : (2.0f / NFFT);
        int p = (f * j) & (NFFT - 1);                 // exact phase reduction
        float ang = (float)p * 6.135923151542565e-03f; // 2*pi/1024
        float s, cs;
        sincosf(ang, &s, &cs);
        re = wt * cs;
        im = -wt * s;
    }
    int off = c * CHUNK_BYTES + j * 128 + ((fl * 4) ^ ((j & 7) << 4));
    *(short2*)(bw + off) = make_short2(f2bf(re), f2bf(im));
}

// fold one chunk's A tile: wave handles fpairs fl=wid*4+i, lanes = 64 segments
template<bool GUARD>
__device__ inline void fold_chunk(const float* __restrict__ fb, char* sA,
                                  int c, int tile, int wid, int lane) {
    const int sl = lane;
    const int s  = tile * 64 + sl + 2;
#pragma unroll
    for (int i = 0; i < 4; ++i) {
        const int fl = wid * 4 + i;
        const int f  = c * 32 + fl;
        float2 v0, v1, v2, v3;
        if (f < NFREQ) {                       // wave-uniform branch
            const float* frow = fb + (size_t)f * (TFR * 2);
            if (GUARD) {
                int t;
                t = s;     v0 = (t >= 0 && t < TFR) ? *(const float2*)(frow + 2 * t) : make_float2(0.f, 0.f);
                t = s - 1; v1 = (t >= 0 && t < TFR) ? *(const float2*)(frow + 2 * t) : make_float2(0.f, 0.f);
                t = s - 2; v2 = (t >= 0 && t < TFR) ? *(const float2*)(frow + 2 * t) : make_float2(0.f, 0.f);
                t = s - 3; v3 = (t >= 0 && t < TFR) ? *(const float2*)(frow + 2 * t) : make_float2(0.f, 0.f);
            } else {
                v0 = *(const float2*)(frow + 2 * s);
                v1 = *(const float2*)(frow + 2 * (s - 1));
                v2 = *(const float2*)(frow + 2 * (s - 2));
                v3 = *(const float2*)(frow + 2 * (s - 3));
            }
        } else {
            v0 = v1 = v2 = v3 = make_float2(0.f, 0.f);
        }
        // V = sum_k v_k * i^{(f&3)*k},  f&3 == i (c*32, wid*4 are mult of 4)
        float vr, vi;
        if (i == 0)      { vr = v0.x + v1.x + v2.x + v3.x;  vi = v0.y + v1.y + v2.y + v3.y; }
        else if (i == 1) { vr = v0.x - v1.y - v2.x + v3.y;  vi = v0.y + v1.x - v2.y - v3.x; }
        else if (i == 2) { vr = v0.x - v1.x + v2.x - v3.x;  vi = v0.y - v1.y + v2.y - v3.y; }
        else             { vr = v0.x + v1.y - v2.x - v3.y;  vi = v0.y - v1.x - v2.y + v3.x; }
        int off = sl * 128 + ((fl * 4) ^ ((sl & 7) << 4));
        *(short2*)(sA + off) = make_short2(f2bf(vr), f2bf(vi));
    }
}

// ---- kernel 2: fold + GEMM.  512 thr = 8 waves (2 m x 4 n). tile 64 segs x 256 j.
__global__ __launch_bounds__(512) void istft_mfma(const float* __restrict__ stft,
                                                  const char* __restrict__ bw,
                                                  float* __restrict__ out) {
    __shared__ float4 smem4[(CHUNK_BYTES + 64 * 128) / 16];  // 32KB Bt + 8KB A
    char* sB = (char*)smem4;
    char* sA = sB + CHUNK_BYTES;

    const int tid  = threadIdx.x;
    const int tile = blockIdx.x, b = blockIdx.y;
    const int lane = tid & 63;
    const int wid  = __builtin_amdgcn_readfirstlane(tid >> 6);
    const int wr   = wid >> 2, wc = wid & 3;
    const bool boundary = (tile == 0) || (tile == NTILE - 1);

    const float* fb = stft + (size_t)b * NFREQ * (TFR * 2);

    f32x4 acc[2][4] = {};

    for (int c = 0; c < NCHUNK; ++c) {
        __syncthreads();  // prev chunk's readers done before overwrite

        // stage Bt chunk (global image == LDS image, linear copy)
        const float4* srcB = (const float4*)(bw + (size_t)c * CHUNK_BYTES);
#pragma unroll
        for (int i = 0; i < 4; ++i) smem4[i * 512 + tid] = srcB[i * 512 + tid];

        // fold A tile: 64 segs x 32 freq-pairs, coalesced along segments
        if (boundary) fold_chunk<true >(fb, sA, c, tile, wid, lane);
        else          fold_chunk<false>(fb, sA, c, tile, wid, lane);
        __syncthreads();

        // MFMA: per wave 2 m-frags x 4 n-frags x 2 k-frags
#pragma unroll
        for (int kf = 0; kf < 2; ++kf) {
            int kbx  = (kf * 64 + (lane >> 4) * 16) ^ ((lane & 7) << 4);
            int arow = (wr * 32 + (lane & 15)) * 128;
            bf16x8 a0 = *(const bf16x8*)(sA + arow + kbx);
            bf16x8 a1 = *(const bf16x8*)(sA + arow + 16 * 128 + kbx);
#pragma unroll
            for (int ni = 0; ni < 4; ++ni) {
                int jrow = (wc * 64 + ni * 16 + (lane & 15)) * 128;
                bf16x8 bfr = *(const bf16x8*)(sB + jrow + kbx);
                acc[0][ni] = __builtin_amdgcn_mfma_f32_16x16x32_bf16(a0, bfr, acc[0][ni], 0, 0, 0);
                acc[1][ni] = __builtin_amdgcn_mfma_f32_16x16x32_bf16(a1, bfr, acc[1][ni], 0, 0, 0);
            }
        }
    }

    // epilogue: C/D layout col=lane&15, row=(lane>>4)*4+reg
#pragma unroll
    for (int mi = 0; mi < 2; ++mi) {
#pragma unroll
        for (int r = 0; r < 4; ++r) {
            int sl = wr * 32 + mi * 16 + (lane >> 4) * 4 + r;
            int seg = tile * 64 + sl;
            if (seg >= NSEG) continue;
            int s = seg + 2;
            int lo = s - 3; lo = lo < 0 ? 0 : lo;
            int hi = s > (TFR - 1) ? (TFR - 1) : s;
            float inv = 1.0f / (float)(hi - lo + 1);
            size_t base = (size_t)b * OUTLEN + (size_t)seg * 256 + wc * 64 + (lane & 15);
#pragma unroll
            for (int ni = 0; ni < 4; ++ni)
                out[base + ni * 16] = acc[mi][ni][r] * inv;
        }
    }
}

// ---- fallback (ws too small): direct VALU kernel ----
__global__ __launch_bounds__(256, 4) void istft_seg_kernel(
    const float* __restrict__ stft, float* __restrict__ out)
{
    __shared__ float2 V[NFREQ];
    const int blk = blockIdx.x;
    const int b = blk / NSEG;
    const int s = (blk % NSEG) + 2;
    const int tid = threadIdx.x;

    const float* fbase = stft + (size_t)b * (size_t)NFREQ * (TFR * 2);
    for (int f = tid; f < NFREQ; f += 256) {
        const float* frow = fbase + (size_t)f * (TFR * 2);
        float vr = 0.0f, vi = 0.0f;
#pragma unroll
        for (int k = 0; k < 4; ++k) {
            int t = s - k;
            if (t < 0 || t >= TFR) continue;
            float2 v = *(const float2*)(frow + 2 * t);
            int e = (f * k) & 3;
            float ar = (e == 0) ? v.x : (e == 1) ? -v.y : (e == 2) ? -v.x :  v.y;
            float ai = (e == 0) ? v.y : (e == 1) ?  v.x : (e == 2) ? -v.y : -v.x;
            vr += ar; vi += ai;
        }
        float scale = (f == 0 || f == NFFT / 2) ? (1.0f / NFFT) : (2.0f / NFFT);
        V[f] = make_float2(vr * scale, vi * scale);
    }
    __syncthreads();

    int tlo = s - 3; if (tlo < 0) tlo = 0;
    int thi = s;     if (thi > TFR - 1) thi = TFR - 1;
    const float inv_w = 1.0f / (float)(thi - tlo + 1);

    const int j = tid;
    double ang = (2.0 * 3.14159265358979323846 / (double)NFFT) * (double)j;
    const float cd = (float)cos(ang);
    const float sd = (float)sin(ang);

    float cc = 1.0f, sn = 0.0f, a = 0.0f;
#pragma unroll 4
    for (int f = 0; f < NFREQ; ++f) {
        float2 v = V[f];
        a = fmaf(v.x, cc, a);
        a = fmaf(-v.y, sn, a);
        float cn = fmaf(cc, cd, -(sn * sd));
        sn       = fmaf(sn, cd,  (cc * sd));
        cc = cn;
    }
    out[(size_t)b * OUTLEN + (size_t)(s - 2) * HOP + j] = a * inv_w;
}

extern "C" void kernel_launch(void* const* d_in, const int* in_sizes, int n_in,
                              void* d_out, int out_size, void* d_ws, size_t ws_size,
                              hipStream_t stream)
{
    const float* stft = (const float*)d_in[0];
    float* out = (float*)d_out;

    if (ws_size >= WS_NEED) {
        char* bw = (char*)d_ws;
        build_basis<<<dim3(NCHUNK * 8192 / 256), dim3(256), 0, stream>>>(bw);
        istft_mfma<<<dim3(NTILE, NB), dim3(512), 0, stream>>>(stft, bw, out);
    } else {
        istft_seg_kernel<<<dim3(NB * NSEG), dim3(256), 0, stream>>>(stft, out);
    }
}

// Round 9
// 232.972 us; speedup vs baseline: 1.4695x; 1.0817x over previous
//
#include <hip/hip_runtime.h>

// iSTFT as fold + bf16 MFMA GEMM (round 6: dbuf B via global_load_lds,
// reg-prefetched fold, conflict-free b128 A writes).
//
// full[f,t] Hermitian -> f=0..512, weight wt={1,2,..,2,1}/1024 folded into basis.
// Output l = 256*s + j (s=2..2002, j=0..255) covered by frames t=s-3..s (clipped).
//   V_s[f] = sum_k full[f,s-k] * i^{f*k}
//   y[seg*256+j] = sum_f [wt*ReV*cos - wt*ImV*sin] / wss
// GEMM: A[seg][k] x W[k][j]; K 1026 -> 1088 (17 chunks of 64).
// Pipeline per chunk: issue glds(B[c+1]) + reg-prefetch(fold[c+1]) -> MFMA(c)
// -> barrier -> fold-compute+A-write -> barrier.

typedef short bf16x8 __attribute__((ext_vector_type(8)));
typedef short short8v __attribute__((ext_vector_type(8)));
typedef float f32x4  __attribute__((ext_vector_type(4)));

constexpr int NFFT = 1024, HOP = 256, NFREQ = 513, TFR = 2000;
constexpr int NB = 16, NSEG = 2001, OUTLEN = NSEG * HOP;
constexpr int NCHUNK = 17;                    // K chunks of 64 (= 32 freq pairs)
constexpr int CHUNK_BYTES = 256 * 128;        // Bt chunk image: 256 j-rows x 128 B
constexpr int NTILE = 32;                     // 32 tiles x 64 segs covers 2001
constexpr size_t WS_NEED = (size_t)NCHUNK * CHUNK_BYTES;   // 557056 B

__device__ inline short f2bf(float x) {      // RNE float->bf16 (finite inputs)
    unsigned u = __float_as_uint(x);
    unsigned r = (u + 0x7fffu + ((u >> 16) & 1u)) >> 16;
    return (short)r;
}

__device__ inline void glds16(const void* g, void* l) {
    __builtin_amdgcn_global_load_lds(
        (const __attribute__((address_space(1))) unsigned*)g,
        (__attribute__((address_space(3))) unsigned*)l, 16, 0, 0);
}

// ---- kernel 1: basis, stored as the swizzled LDS image per chunk ----
// Wt[j][k] bf16, row j = 128 B; byte within row for freq-pair fl: (fl*4)^((j&7)<<4)
__global__ void build_basis(char* __restrict__ bw) {
    int id = blockIdx.x * 256 + threadIdx.x;  // 17 * 8192 total
    int c = id >> 13, r = id & 8191, j = r >> 5, fl = r & 31;
    int f = c * 32 + fl;
    float re = 0.f, im = 0.f;
    if (f < NFREQ) {
        float wt = (f == 0 || f == NFFT / 2) ? (1.0f / NFFT) : (2.0f / NFFT);
        int p = (f * j) & (NFFT - 1);                 // exact phase reduction
        float ang = (float)p * 6.135923151542565e-03f; // 2*pi/1024
        float s, cs;
        sincosf(ang, &s, &cs);
        re = wt * cs;
        im = -wt * s;
    }
    int off = c * CHUNK_BYTES + j * 128 + ((fl * 4) ^ ((j & 7) << 4));
    *(short2*)(bw + off) = make_short2(f2bf(re), f2bf(im));
}

// prefetch fold inputs for one chunk into regs: wave-uniform f, lanes = 64 segs
template<bool GUARD>
__device__ inline void prefetch_fold(const float* __restrict__ fb, int c, int tile,
                                     int wid, int lane, float2 fr[4][4]) {
    const int s = tile * 64 + lane + 2;
#pragma unroll
    for (int i = 0; i < 4; ++i) {
        const int fl = wid * 4 + i;
        const int f  = c * 32 + fl;
        if (f < NFREQ) {                       // wave-uniform branch
            const float* frow = fb + (size_t)f * (TFR * 2);
#pragma unroll
            for (int k = 0; k < 4; ++k) {
                int t = s - k;
                if (GUARD)
                    fr[i][k] = (t >= 0 && t < TFR) ? *(const float2*)(frow + 2 * t)
                                                   : make_float2(0.f, 0.f);
                else
                    fr[i][k] = *(const float2*)(frow + 2 * t);
            }
        } else {
#pragma unroll
            for (int k = 0; k < 4; ++k) fr[i][k] = make_float2(0.f, 0.f);
        }
    }
}

// fold i^{f*k} sign-combine (f&3 == i) and single b128 A write (conflict-free)
__device__ inline void fold_write(char* sA, int wid, int lane, float2 fr[4][4]) {
    short8v o;
#pragma unroll
    for (int i = 0; i < 4; ++i) {
        float2 v0 = fr[i][0], v1 = fr[i][1], v2 = fr[i][2], v3 = fr[i][3];
        float vr, vi;
        if (i == 0)      { vr = v0.x + v1.x + v2.x + v3.x;  vi = v0.y + v1.y + v2.y + v3.y; }
        else if (i == 1) { vr = v0.x - v1.y - v2.x + v3.y;  vi = v0.y + v1.x - v2.y - v3.x; }
        else if (i == 2) { vr = v0.x - v1.x + v2.x - v3.x;  vi = v0.y - v1.y + v2.y - v3.y; }
        else             { vr = v0.x + v1.y - v2.x - v3.y;  vi = v0.y - v1.x - v2.y + v3.x; }
        o[2 * i]     = f2bf(vr);
        o[2 * i + 1] = f2bf(vi);
    }
    // bytes [wid*16, wid*16+16) of row `lane`, XOR-swizzled: contiguous 16 B
    *(short8v*)(sA + lane * 128 + ((wid * 16) ^ ((lane & 7) << 4))) = o;
}

// ---- kernel 2: fold + GEMM.  512 thr = 8 waves (2 m x 4 n). tile 64 segs x 256 j.
__global__ __launch_bounds__(512) void istft_mfma(const float* __restrict__ stft,
                                                  const char* __restrict__ bw,
                                                  float* __restrict__ out) {
    __shared__ float4 smem4[(2 * CHUNK_BYTES + 64 * 128) / 16];  // 64KB Bx2 + 8KB A
    char* sB0 = (char*)smem4;
    char* sB1 = sB0 + CHUNK_BYTES;
    char* sA  = sB0 + 2 * CHUNK_BYTES;

    const int tid  = threadIdx.x;
    const int tile = blockIdx.x, b = blockIdx.y;
    const int lane = tid & 63;
    const int wid  = __builtin_amdgcn_readfirstlane(tid >> 6);
    const int wr   = wid >> 2, wc = wid & 3;
    const bool boundary = (tile == 0) || (tile == NTILE - 1);

    const float* fb = stft + (size_t)b * NFREQ * (TFR * 2);

    // async B stage: 8 waves x 4 x 1KB = 32KB, linear image
    auto stageB = [&](int c, char* dst) {
#pragma unroll
        for (int i = 0; i < 4; ++i) {
            int off = (wid * 4 + i) * 1024;
            glds16(bw + (size_t)c * CHUNK_BYTES + off + lane * 16, dst + off);
        }
    };

    f32x4 acc[2][4] = {};
    float2 fr[4][4];

    // prologue: chunk 0
    stageB(0, sB0);
    if (boundary) prefetch_fold<true >(fb, 0, tile, wid, lane, fr);
    else          prefetch_fold<false>(fb, 0, tile, wid, lane, fr);
    fold_write(sA, wid, lane, fr);
    __syncthreads();   // drains glds(B0), publishes A0

    for (int c = 0; c < NCHUNK; ++c) {
        const char* sBc = (c & 1) ? sB1 : sB0;
        char*       sBn = (c & 1) ? sB0 : sB1;

        if (c + 1 < NCHUNK) {
            stageB(c + 1, sBn);                    // async, other buffer
            if (boundary) prefetch_fold<true >(fb, c + 1, tile, wid, lane, fr);
            else          prefetch_fold<false>(fb, c + 1, tile, wid, lane, fr);
        }

        // MFMA: per wave 2 m-frags x 4 n-frags x 2 k-frags (loads in flight above)
#pragma unroll
        for (int kf = 0; kf < 2; ++kf) {
            int kbx  = (kf * 64 + (lane >> 4) * 16) ^ ((lane & 7) << 4);
            int arow = (wr * 32 + (lane & 15)) * 128;
            bf16x8 a0 = *(const bf16x8*)(sA + arow + kbx);
            bf16x8 a1 = *(const bf16x8*)(sA + arow + 16 * 128 + kbx);
#pragma unroll
            for (int ni = 0; ni < 4; ++ni) {
                int jrow = (wc * 64 + ni * 16 + (lane & 15)) * 128;
                bf16x8 bfr = *(const bf16x8*)(sBc + jrow + kbx);
                acc[0][ni] = __builtin_amdgcn_mfma_f32_16x16x32_bf16(a0, bfr, acc[0][ni], 0, 0, 0);
                acc[1][ni] = __builtin_amdgcn_mfma_f32_16x16x32_bf16(a1, bfr, acc[1][ni], 0, 0, 0);
            }
        }
        __syncthreads();   // A consumed by all waves; drains glds(B[c+1]) + fr
        if (c + 1 < NCHUNK) fold_write(sA, wid, lane, fr);
        __syncthreads();   // publish A[c+1] (B[c+1] already landed)
    }

    // epilogue: C/D layout col=lane&15, row=(lane>>4)*4+reg
#pragma unroll
    for (int mi = 0; mi < 2; ++mi) {
#pragma unroll
        for (int r = 0; r < 4; ++r) {
            int sl = wr * 32 + mi * 16 + (lane >> 4) * 4 + r;
            int seg = tile * 64 + sl;
            if (seg >= NSEG) continue;
            int s = seg + 2;
            int lo = s - 3; lo = lo < 0 ? 0 : lo;
            int hi = s > (TFR - 1) ? (TFR - 1) : s;
            float inv = 1.0f / (float)(hi - lo + 1);
            size_t base = (size_t)b * OUTLEN + (size_t)seg * 256 + wc * 64 + (lane & 15);
#pragma unroll
            for (int ni = 0; ni < 4; ++ni)
                out[base + ni * 16] = acc[mi][ni][r] * inv;
        }
    }
}

// ---- fallback (ws too small): direct VALU kernel ----
__global__ __launch_bounds__(256, 4) void istft_seg_kernel(
    const float* __restrict__ stft, float* __restrict__ out)
{
    __shared__ float2 V[NFREQ];
    const int blk = blockIdx.x;
    const int b = blk / NSEG;
    const int s = (blk % NSEG) + 2;
    const int tid = threadIdx.x;

    const float* fbase = stft + (size_t)b * (size_t)NFREQ * (TFR * 2);
    for (int f = tid; f < NFREQ; f += 256) {
        const float* frow = fbase + (size_t)f * (TFR * 2);
        float vr = 0.0f, vi = 0.0f;
#pragma unroll
        for (int k = 0; k < 4; ++k) {
            int t = s - k;
            if (t < 0 || t >= TFR) continue;
            float2 v = *(const float2*)(frow + 2 * t);
            int e = (f * k) & 3;
            float ar = (e == 0) ? v.x : (e == 1) ? -v.y : (e == 2) ? -v.x :  v.y;
            float ai = (e == 0) ? v.y : (e == 1) ?  v.x : (e == 2) ? -v.y : -v.x;
            vr += ar; vi += ai;
        }
        float scale = (f == 0 || f == NFFT / 2) ? (1.0f / NFFT) : (2.0f / NFFT);
        V[f] = make_float2(vr * scale, vi * scale);
    }
    __syncthreads();

    int tlo = s - 3; if (tlo < 0) tlo = 0;
    int thi = s;     if (thi > TFR - 1) thi = TFR - 1;
    const float inv_w = 1.0f / (float)(thi - tlo + 1);

    const int j = tid;
    double ang = (2.0 * 3.14159265358979323846 / (double)NFFT) * (double)j;
    const float cd = (float)cos(ang);
    const float sd = (float)sin(ang);

    float cc = 1.0f, sn = 0.0f, a = 0.0f;
#pragma unroll 4
    for (int f = 0; f < NFREQ; ++f) {
        float2 v = V[f];
        a = fmaf(v.x, cc, a);
        a = fmaf(-v.y, sn, a);
        float cn = fmaf(cc, cd, -(sn * sd));
        sn       = fmaf(sn, cd,  (cc * sd));
        cc = cn;
    }
    out[(size_t)b * OUTLEN + (size_t)(s - 2) * HOP + j] = a * inv_w;
}

extern "C" void kernel_launch(void* const* d_in, const int* in_sizes, int n_in,
                              void* d_out, int out_size, void* d_ws, size_t ws_size,
                              hipStream_t stream)
{
    const float* stft = (const float*)d_in[0];
    float* out = (float*)d_out;

    if (ws_size >= WS_NEED) {
        char* bw = (char*)d_ws;
        build_basis<<<dim3(NCHUNK * 8192 / 256), dim3(256), 0, stream>>>(bw);
        istft_mfma<<<dim3(NTILE, NB), dim3(512), 0, stream>>>(stft, bw, out);
    } else {
        istft_seg_kernel<<<dim3(NB * NSEG), dim3(256), 0, stream>>>(stft, out);
    }
}